// Round 2
// baseline (714.413 us; speedup 1.0000x reference)
//
#include <hip/hip_runtime.h>

// NeuralODE: z0 = enc(y0); 100 x Tsit5 steps of f = W3 tanh(W2 tanh(W1 y + b1) + b2) + b3;
// outputs ys = dec(z_t), zs = z_t.  Grid 256 blocks x 128 thr (2 waves).
//   wave 0: the serial ODE chain for 16 batch elements (pure compute, no global stores)
//   wave 1: consumes z_s via double-buffered LDS, does store_z + decoder MFMAs + stores
//
// GEMM orientation: D[row, elem] = W[row, k] * Act[k, elem] with mfma_f32_16x16x32_f16.
// Lane l = (e = l&15, q = l>>4). C/D: lane holds rows p = 16t+4q+r (t = M-tile, r = reg).
// Consumer weight k-columns are pre-shuffled by kappa so the producer's C/D registers
// ARE the consumer's lane-local B-fragment (see load_wfrag slot mapping).
// 3-term f16 hi/lo split (Whi*Bhi + Wlo*Bhi + Whi*Blo) keeps per-product error ~2^-22.
// This revision: the 3 terms go to INDEPENDENT accumulators (aA/aB/aC) merged with two
// f32x4 adds -> dependent-MFMA chain per eval drops from 6/3/3 to 2/1/1 (latency-bound,
// 1 wave/SIMD: critical-path latency IS wall time).
// tanh input scale 2/ln2 folded into W1,b1,W2,b2; dt folded into Butcher coefficients;
// running stage accumulators so each k_i dies immediately.

typedef __attribute__((ext_vector_type(8))) _Float16 half8;
typedef __attribute__((ext_vector_type(4))) float f32x4;

static constexpr int TN = 101;
static constexpr int BN = 4096;

#define MFMA(a, b, c) __builtin_amdgcn_mfma_f32_16x16x32_f16((a), (b), (c), 0, 0, 0)

__device__ __forceinline__ float tanh_pre(float x) {
  // input already scaled by 2/ln2: tanh = 1 - 2/(1+2^x); exact at +/-inf via exp2 range.
  float e = __builtin_amdgcn_exp2f(x);
  float r = __builtin_amdgcn_rcpf(e + 1.0f);
  return __builtin_fmaf(-2.0f, r, 1.0f);
}

__device__ __forceinline__ void split8(const float* v, half8& hi, half8& lo) {
#pragma unroll
  for (int j = 0; j < 8; ++j) {
    _Float16 h = (_Float16)v[j];
    hi[j] = h;
    lo[j] = (_Float16)(v[j] - (float)h);
  }
}

// A-fragment for a weight whose k-columns are consumed kappa-shuffled:
// slot j of lane q, K-tile kt  <-  W[row][kt*32 + 16*(j>>2) + 4*q + (j&3)] * scale
__device__ __forceinline__ void load_wfrag(const float* __restrict__ W, int C, int row, int q,
                                           int kt, float scale, half8& hi, half8& lo) {
  const float* p = W + row * C + kt * 32 + 4 * q;
  float v[8] __attribute__((aligned(16)));
  *(f32x4*)(v) = *(const f32x4*)(p);
  *(f32x4*)(v + 4) = *(const f32x4*)(p + 16);
#pragma unroll
  for (int j = 0; j < 8; ++j) v[j] *= scale;
  split8(v, hi, lo);
}

__global__ __launch_bounds__(128, 1) void node_kernel(
    const float* __restrict__ ts, const float* __restrict__ y0,
    const float* __restrict__ encW, const float* __restrict__ encb,
    const float* __restrict__ W1, const float* __restrict__ b1,
    const float* __restrict__ W2, const float* __restrict__ b2,
    const float* __restrict__ W3, const float* __restrict__ b3,
    const float* __restrict__ decW, const float* __restrict__ decb,
    float* __restrict__ out) {
  const int tid = threadIdx.x;
  const int wid = tid >> 6;
  const int l = tid & 63;
  const int lm = l & 15;
  const int q = l >> 4;
  const int eg = blockIdx.x * 16 + lm;

  __shared__ f32x4 lbuf[2][4][64];  // z handoff, double-buffered by step parity

  if (wid == 1) {
    // ---- output wave: decoder frags in registers, consume z_s from LDS ----
    half8 dech[4][2];
    f32x4 decbf[4];
#pragma unroll
    for (int mt = 0; mt < 4; ++mt) {
#pragma unroll
      for (int kt = 0; kt < 2; ++kt) {
        const float* p = decW + (16 * mt + lm) * 64 + kt * 32 + 4 * q;
        float v[8] __attribute__((aligned(16)));
        *(f32x4*)(v) = *(const f32x4*)(p);
        *(f32x4*)(v + 4) = *(const f32x4*)(p + 16);
        half8 h;
#pragma unroll
        for (int j = 0; j < 8; ++j) h[j] = (_Float16)v[j];
        dech[mt][kt] = h;
      }
      decbf[mt] = *(const f32x4*)(decb + 16 * mt + 4 * q);
    }
#pragma nounroll
    for (int s = 0; s < TN; ++s) {
      __syncthreads();  // wave 0 has published z_s into lbuf[s&1]
      f32x4 x[4];
#pragma unroll
      for (int t = 0; t < 4; ++t) x[t] = lbuf[s & 1][t][l];
      // zs output (true dim order: row p = 16t+4q+r)
      float* zb = out + (size_t)BN * TN * 64 + ((size_t)eg * TN + s) * 64;
#pragma unroll
      for (int t = 0; t < 4; ++t) *(f32x4*)(zb + 16 * t + 4 * q) = x[t];
      // ys = dec(z_s) (single f16: decoder error does not feed back)
      half8 xh[2];
#pragma unroll
      for (int j = 0; j < 4; ++j) {
        xh[0][j] = (_Float16)x[0][j];
        xh[0][4 + j] = (_Float16)x[1][j];
        xh[1][j] = (_Float16)x[2][j];
        xh[1][4 + j] = (_Float16)x[3][j];
      }
      float* yb = out + ((size_t)eg * TN + s) * 64;
#pragma unroll
      for (int mt = 0; mt < 4; ++mt) {
        f32x4 a = decbf[mt];
        a = MFMA(dech[mt][0], xh[0], a);
        a = MFMA(dech[mt][1], xh[1], a);
        *(f32x4*)(yb + 16 * mt + 4 * q) = a;
      }
    }
    return;
  }

  // ======================= wave 0: the ODE chain =======================
  const float TS = 2.8853900817779268f;  // 2/ln2, folded into W1,b1,W2,b2

  // ---- persistent MLP weight fragments (f16 hi+lo) ----
  half8 w1h[2][2], w1l[2][2], w2h[2], w2l[2], w3h[4], w3l[4];
#pragma unroll
  for (int mt = 0; mt < 2; ++mt) {
#pragma unroll
    for (int kt = 0; kt < 2; ++kt)
      load_wfrag(W1, 64, 16 * mt + lm, q, kt, TS, w1h[mt][kt], w1l[mt][kt]);
    load_wfrag(W2, 32, 16 * mt + lm, q, 0, TS, w2h[mt], w2l[mt]);
  }
#pragma unroll
  for (int mt = 0; mt < 4; ++mt) load_wfrag(W3, 32, 16 * mt + lm, q, 0, 1.0f, w3h[mt], w3l[mt]);

  f32x4 b1f[2], b2f[2], b3f[4];
#pragma unroll
  for (int mt = 0; mt < 2; ++mt) {
    f32x4 t1 = *(const f32x4*)(b1 + 16 * mt + 4 * q);
    f32x4 t2 = *(const f32x4*)(b2 + 16 * mt + 4 * q);
#pragma unroll
    for (int r = 0; r < 4; ++r) {
      t1[r] *= TS;
      t2[r] *= TS;
    }
    b1f[mt] = t1;
    b2f[mt] = t2;
  }
#pragma unroll
  for (int mt = 0; mt < 4; ++mt) b3f[mt] = *(const f32x4*)(b3 + 16 * mt + 4 * q);

  float z[16];

  // ---- encoder: z0 = encW * y0^T + encb (enc cols in TRUE order; y0 frag = 8 consecutive) ----
  {
    const float* yp = y0 + (size_t)eg * 64;
    float v[16] __attribute__((aligned(16)));
    *(f32x4*)(v) = *(const f32x4*)(yp + 8 * q);
    *(f32x4*)(v + 4) = *(const f32x4*)(yp + 8 * q + 4);
    *(f32x4*)(v + 8) = *(const f32x4*)(yp + 32 + 8 * q);
    *(f32x4*)(v + 12) = *(const f32x4*)(yp + 32 + 8 * q + 4);
    half8 xh[2], xl[2];
    split8(v, xh[0], xl[0]);
    split8(v + 8, xh[1], xl[1]);
#pragma unroll
    for (int mt = 0; mt < 4; ++mt) {
      const float* p0 = encW + (16 * mt + lm) * 64 + 8 * q;
      float w[8] __attribute__((aligned(16)));
      half8 eh, el;
      f32x4 a = *(const f32x4*)(encb + 16 * mt + 4 * q);
      *(f32x4*)(w) = *(const f32x4*)(p0);
      *(f32x4*)(w + 4) = *(const f32x4*)(p0 + 4);
      split8(w, eh, el);
      a = MFMA(eh, xh[0], a);
      a = MFMA(el, xh[0], a);
      a = MFMA(eh, xl[0], a);
      *(f32x4*)(w) = *(const f32x4*)(p0 + 32);
      *(f32x4*)(w + 4) = *(const f32x4*)(p0 + 36);
      split8(w, eh, el);
      a = MFMA(eh, xh[1], a);
      a = MFMA(el, xh[1], a);
      a = MFMA(eh, xl[1], a);
#pragma unroll
      for (int r = 0; r < 4; ++r) z[4 * mt + r] = a[r];
    }
  }

  // ---- f: 3-term products in INDEPENDENT accumulators, merged with 2 f32x4 adds ----
  auto evalf = [&](const float (&yv)[16], float (&kv)[16]) {
    const f32x4 zero = {0.0f, 0.0f, 0.0f, 0.0f};
    half8 yh[2], yl[2];
    split8(yv, yh[0], yl[0]);
    split8(yv + 8, yh[1], yl[1]);
    float h1[8], h2[8];
#pragma unroll
    for (int mt = 0; mt < 2; ++mt) {
      f32x4 aA = b1f[mt], aB = zero, aC = zero;
      aA = MFMA(w1h[mt][0], yh[0], aA);
      aB = MFMA(w1l[mt][0], yh[0], aB);
      aC = MFMA(w1h[mt][0], yl[0], aC);
      aA = MFMA(w1h[mt][1], yh[1], aA);
      aB = MFMA(w1l[mt][1], yh[1], aB);
      aC = MFMA(w1h[mt][1], yl[1], aC);
      f32x4 a = aA + (aB + aC);
#pragma unroll
      for (int r = 0; r < 4; ++r) h1[4 * mt + r] = tanh_pre(a[r]);
    }
    half8 hh, hl;
    split8(h1, hh, hl);
#pragma unroll
    for (int mt = 0; mt < 2; ++mt) {
      f32x4 aA = MFMA(w2h[mt], hh, b2f[mt]);
      f32x4 aB = MFMA(w2l[mt], hh, zero);
      f32x4 aC = MFMA(w2h[mt], hl, zero);
      f32x4 a = aA + (aB + aC);
#pragma unroll
      for (int r = 0; r < 4; ++r) h2[4 * mt + r] = tanh_pre(a[r]);
    }
    split8(h2, hh, hl);
#pragma unroll
    for (int mt = 0; mt < 4; ++mt) {
      f32x4 aA = MFMA(w3h[mt], hh, b3f[mt]);
      f32x4 aB = MFMA(w3l[mt], hh, zero);
      f32x4 aC = MFMA(w3h[mt], hl, zero);
      f32x4 a = aA + (aB + aC);
#pragma unroll
      for (int r = 0; r < 4; ++r) kv[4 * mt + r] = a[r];
    }
  };

  auto publish = [&](const float (&x)[16], int s) {
#pragma unroll
    for (int t = 0; t < 4; ++t) {
      f32x4 v = {x[4 * t], x[4 * t + 1], x[4 * t + 2], x[4 * t + 3]};
      lbuf[s & 1][t][l] = v;
    }
    __syncthreads();
  };

  // ---- dt-folded Butcher coefficients (wave-uniform scalars) ----
  const float dt = (ts[TN - 1] - ts[0]) / (float)(TN - 1);
  const float c21 = dt * 0.161f;
  const float c31 = dt * -0.008480655492356989f, c32 = dt * 0.335480655492357f;
  const float c41 = dt * 2.8971530571054935f, c42 = dt * -6.359448489975075f,
              c43 = dt * 4.3622954328695815f;
  const float c51 = dt * 5.325864828439257f, c52 = dt * -11.748883564062828f,
              c53 = dt * 7.4955393428898365f, c54 = dt * -0.09249506636175525f;
  const float c61 = dt * 5.86145544294642f, c62 = dt * -12.92096931784711f,
              c63 = dt * 8.159367898576159f, c64 = dt * -0.071584973281401f,
              c65 = dt * -0.028269050394068383f;
  const float d1 = dt * 0.09646076681806523f, d2 = dt * 0.01f, d3 = dt * 0.4798896504144996f,
              d4 = dt * 1.379008574103742f, d5 = dt * -3.290069515436081f,
              d6 = dt * 2.324710524099774f;

  publish(z, 0);

#pragma nounroll
  for (int s = 1; s < TN; ++s) {
    float k[16], y2[16], y3[16], y4[16], y5[16], y6[16], zn[16];
    evalf(z, k);  // k1
#pragma unroll
    for (int i = 0; i < 16; ++i) {
      y2[i] = __builtin_fmaf(c21, k[i], z[i]);
      y3[i] = __builtin_fmaf(c31, k[i], z[i]);
      y4[i] = __builtin_fmaf(c41, k[i], z[i]);
      y5[i] = __builtin_fmaf(c51, k[i], z[i]);
      y6[i] = __builtin_fmaf(c61, k[i], z[i]);
      zn[i] = __builtin_fmaf(d1, k[i], z[i]);
    }
    evalf(y2, k);  // k2
#pragma unroll
    for (int i = 0; i < 16; ++i) {
      y3[i] = __builtin_fmaf(c32, k[i], y3[i]);
      y4[i] = __builtin_fmaf(c42, k[i], y4[i]);
      y5[i] = __builtin_fmaf(c52, k[i], y5[i]);
      y6[i] = __builtin_fmaf(c62, k[i], y6[i]);
      zn[i] = __builtin_fmaf(d2, k[i], zn[i]);
    }
    evalf(y3, k);  // k3
#pragma unroll
    for (int i = 0; i < 16; ++i) {
      y4[i] = __builtin_fmaf(c43, k[i], y4[i]);
      y5[i] = __builtin_fmaf(c53, k[i], y5[i]);
      y6[i] = __builtin_fmaf(c63, k[i], y6[i]);
      zn[i] = __builtin_fmaf(d3, k[i], zn[i]);
    }
    evalf(y4, k);  // k4
#pragma unroll
    for (int i = 0; i < 16; ++i) {
      y5[i] = __builtin_fmaf(c54, k[i], y5[i]);
      y6[i] = __builtin_fmaf(c64, k[i], y6[i]);
      zn[i] = __builtin_fmaf(d4, k[i], zn[i]);
    }
    evalf(y5, k);  // k5
#pragma unroll
    for (int i = 0; i < 16; ++i) {
      y6[i] = __builtin_fmaf(c65, k[i], y6[i]);
      zn[i] = __builtin_fmaf(d5, k[i], zn[i]);
    }
    evalf(y6, k);  // k6
#pragma unroll
    for (int i = 0; i < 16; ++i) z[i] = __builtin_fmaf(d6, k[i], zn[i]);
    publish(z, s);
  }
}

extern "C" void kernel_launch(void* const* d_in, const int* in_sizes, int n_in,
                              void* d_out, int out_size, void* d_ws, size_t ws_size,
                              hipStream_t stream) {
  const float* ts = (const float*)d_in[0];
  const float* y0 = (const float*)d_in[1];
  const float* encW = (const float*)d_in[2];
  const float* encb = (const float*)d_in[3];
  const float* W1 = (const float*)d_in[4];
  const float* b1 = (const float*)d_in[5];
  const float* W2 = (const float*)d_in[6];
  const float* b2 = (const float*)d_in[7];
  const float* W3 = (const float*)d_in[8];
  const float* b3 = (const float*)d_in[9];
  const float* decW = (const float*)d_in[10];
  const float* decb = (const float*)d_in[11];
  node_kernel<<<BN / 16, 128, 0, stream>>>(ts, y0, encW, encb, W1, b1, W2, b2, W3, b3, decW,
                                           decb, (float*)d_out);
}

// Round 3
// 469.466 us; speedup vs baseline: 1.5218x; 1.5218x over previous
//
#include <hip/hip_runtime.h>

// NeuralODE: z0 = enc(y0); 100 x Tsit5 steps of f = W3 tanh(W2 tanh(W1 y + b1) + b2) + b3;
// outputs ys = dec(z_t), zs = z_t.  One wave (64 thr) per 16 batch elements, grid 256.
//
// === Chain-shortening algebra (this revision) ===
// Stage inputs are y_i = z + sum_j a_ij k_j and k = W3 h2 + b3.  Track the TS-scaled
// pre-activation u = TS*(W1 y + b1) (32-dim) instead of y (64-dim).  With
//   M  = TS * W1 * W3   (32x32, fused, computed once per wave in f32)
//   c0 = TS * W1 * b3   (32-vec)
// each stage is: h1 = tanh(p); q = TSW2 h1 + TSb2; h2 = tanh(q); m = M h2;
//   p_next = u + sig*c0-part + sum a*m   (running accumulators P3..P6, U)
// L1 and L3 are OFF the per-stage critical chain.  z is materialized once per step,
// off-path:  z_next = z + W3*(sum dtB_i h2_i) + dt*b3  (12 MFMAs), only for outputs.
//
// GEMM orientation: D[row, elem] = W[row, k] * Act[k, elem] with mfma_f32_16x16x32_f16.
// Lane l = (e = l&15, q = l>>4). C/D: lane holds rows p = 16t+4q+r (t = M-tile, r = reg).
// Consumer weight k-columns are pre-shuffled by kappa so the producer's C/D registers
// ARE the consumer's lane-local B-fragment: A-frag slot j <- W[row][16*(j>>2)+4*q+(j&3)]
// (per 32-wide K-tile).  M is consumed exactly like W2 (B = split of a C/D-order vector),
// so its fragment uses the same mapping.  3-term f16 hi/lo split (Whi*Bhi+Wlo*Bhi+Whi*Blo)
// keeps per-product error ~2^-22; m stays f32 so tiny Butcher coefficients never pass
// through f16 (no subnormal-lo hazard).

typedef __attribute__((ext_vector_type(8))) _Float16 half8;
typedef __attribute__((ext_vector_type(4))) float f32x4;

static constexpr int TN = 101;
static constexpr int BN = 4096;

#define MFMA(a, b, c) __builtin_amdgcn_mfma_f32_16x16x32_f16((a), (b), (c), 0, 0, 0)

__device__ __forceinline__ float tanh_pre(float x) {
  // input already scaled by 2/ln2: tanh = 1 - 2/(1+2^x); exact at +/-inf via exp2 range.
  float e = __builtin_amdgcn_exp2f(x);
  float r = __builtin_amdgcn_rcpf(e + 1.0f);
  return __builtin_fmaf(-2.0f, r, 1.0f);
}

__device__ __forceinline__ void split8(const float* v, half8& hi, half8& lo) {
#pragma unroll
  for (int j = 0; j < 8; ++j) {
    _Float16 h = (_Float16)v[j];
    hi[j] = h;
    lo[j] = (_Float16)(v[j] - (float)h);
  }
}

// A-fragment for a weight whose k-columns are consumed kappa-shuffled:
// slot j of lane q, K-tile kt  <-  W[row][kt*32 + 16*(j>>2) + 4*q + (j&3)] * scale
__device__ __forceinline__ void load_wfrag(const float* __restrict__ W, int C, int row, int q,
                                           int kt, float scale, half8& hi, half8& lo) {
  const float* p = W + row * C + kt * 32 + 4 * q;
  float v[8] __attribute__((aligned(16)));
  *(f32x4*)(v) = *(const f32x4*)(p);
  *(f32x4*)(v + 4) = *(const f32x4*)(p + 16);
#pragma unroll
  for (int j = 0; j < 8; ++j) v[j] *= scale;
  split8(v, hi, lo);
}

__global__ __launch_bounds__(64, 1) void node_kernel(
    const float* __restrict__ ts, const float* __restrict__ y0,
    const float* __restrict__ encW, const float* __restrict__ encb,
    const float* __restrict__ W1, const float* __restrict__ b1,
    const float* __restrict__ W2, const float* __restrict__ b2,
    const float* __restrict__ W3, const float* __restrict__ b3,
    const float* __restrict__ decW, const float* __restrict__ decb,
    float* __restrict__ out) {
  const int l = threadIdx.x;
  const int lm = l & 15;
  const int q = l >> 4;
  const int eg = blockIdx.x * 16 + lm;

  const float TS = 2.8853900817779268f;  // 2/ln2

  // ---- dt and dt-folded Butcher coefficients ----
  const float dt = (ts[TN - 1] - ts[0]) / (float)(TN - 1);
  const float c21 = dt * 0.161f;
  const float c31 = dt * -0.008480655492356989f, c32 = dt * 0.335480655492357f;
  const float c41 = dt * 2.8971530571054935f, c42 = dt * -6.359448489975075f,
              c43 = dt * 4.3622954328695815f;
  const float c51 = dt * 5.325864828439257f, c52 = dt * -11.748883564062828f,
              c53 = dt * 7.4955393428898365f, c54 = dt * -0.09249506636175525f;
  const float c61 = dt * 5.86145544294642f, c62 = dt * -12.92096931784711f,
              c63 = dt * 8.159367898576159f, c64 = dt * -0.071584973281401f,
              c65 = dt * -0.028269050394068383f;
  const float d1 = dt * 0.09646076681806523f, d2 = dt * 0.01f, d3 = dt * 0.4798896504144996f,
              d4 = dt * 1.379008574103742f, d5 = dt * -3.290069515436081f,
              d6 = dt * 2.324710524099774f;
  // stage-node sums sig_j = dt * c_j (row sums of A): multiply c0
  const float sg3 = dt * 0.327f, sg4 = dt * 0.9f, sg5 = dt * 0.9800255409045097f,
              sg6 = dt * 1.0f;

  // ---- persistent weight fragments ----
  half8 w2h[2], w2l[2], w3h[4], w3l[4];
#pragma unroll
  for (int mt = 0; mt < 2; ++mt) load_wfrag(W2, 32, 16 * mt + lm, q, 0, TS, w2h[mt], w2l[mt]);
#pragma unroll
  for (int mt = 0; mt < 4; ++mt) load_wfrag(W3, 32, 16 * mt + lm, q, 0, 1.0f, w3h[mt], w3l[mt]);

  f32x4 b2f[2], db3f[4];
#pragma unroll
  for (int mt = 0; mt < 2; ++mt) {
    f32x4 t2 = *(const f32x4*)(b2 + 16 * mt + 4 * q);
#pragma unroll
    for (int r = 0; r < 4; ++r) t2[r] *= TS;
    b2f[mt] = t2;
  }
#pragma unroll
  for (int mt = 0; mt < 4; ++mt) {
    f32x4 t3 = *(const f32x4*)(b3 + 16 * mt + 4 * q);
#pragma unroll
    for (int r = 0; r < 4; ++r) t3[r] *= dt;
    db3f[mt] = t3;
  }

  // ---- decoder frags in registers (single f16: decoder error does not feed back) ----
  half8 dech[4][2];
  f32x4 decbf[4];
#pragma unroll
  for (int mt = 0; mt < 4; ++mt) {
#pragma unroll
    for (int kt = 0; kt < 2; ++kt) {
      const float* p = decW + (16 * mt + lm) * 64 + kt * 32 + 4 * q;
      float v[8] __attribute__((aligned(16)));
      *(f32x4*)(v) = *(const f32x4*)(p);
      *(f32x4*)(v + 4) = *(const f32x4*)(p + 16);
      half8 h;
#pragma unroll
      for (int j = 0; j < 8; ++j) h[j] = (_Float16)v[j];
      dech[mt][kt] = h;
    }
    decbf[mt] = *(const f32x4*)(decb + 16 * mt + 4 * q);
  }

  // ---- fused M = TS * W1 * W3 (A-frag layout, f32 dots -> hi/lo split) ----
  half8 Mh[2], Ml[2];
  {
    float Mv0[8] = {0, 0, 0, 0, 0, 0, 0, 0};
    float Mv1[8] = {0, 0, 0, 0, 0, 0, 0, 0};
    const float* w1a = W1 + (size_t)lm * 64;
    const float* w1b = W1 + (size_t)(16 + lm) * 64;
    for (int k = 0; k < 64; ++k) {
      float a = w1a[k], b = w1b[k];
      const float* w3r = W3 + (size_t)k * 32 + 4 * q;
#pragma unroll
      for (int jj = 0; jj < 2; ++jj) {  // jj = j>>2 selects +0 / +16 column block
#pragma unroll
        for (int r = 0; r < 4; ++r) {
          float w3v = w3r[16 * jj + r];
          Mv0[4 * jj + r] = __builtin_fmaf(a, w3v, Mv0[4 * jj + r]);
          Mv1[4 * jj + r] = __builtin_fmaf(b, w3v, Mv1[4 * jj + r]);
        }
      }
    }
#pragma unroll
    for (int j = 0; j < 8; ++j) {
      Mv0[j] *= TS;
      Mv1[j] *= TS;
    }
    split8(Mv0, Mh[0], Ml[0]);
    split8(Mv1, Mh[1], Ml[1]);
  }

  // ---- c0 = TS * W1 * b3 in C/D layout: rows 16*mt + 4*q + r ----
  float c0[8] = {0, 0, 0, 0, 0, 0, 0, 0};
  {
    for (int k = 0; k < 64; ++k) {
      float bk = b3[k];
#pragma unroll
      for (int mt = 0; mt < 2; ++mt)
#pragma unroll
        for (int r = 0; r < 4; ++r)
          c0[4 * mt + r] =
              __builtin_fmaf(W1[(size_t)(16 * mt + 4 * q + r) * 64 + k], bk, c0[4 * mt + r]);
    }
#pragma unroll
    for (int j = 0; j < 8; ++j) c0[j] *= TS;
  }

  // ---- encoder: z0 = encW * y0^T + encb ----
  f32x4 zf[4];
  {
    const float* yp = y0 + (size_t)eg * 64;
    float v[16] __attribute__((aligned(16)));
    *(f32x4*)(v) = *(const f32x4*)(yp + 8 * q);
    *(f32x4*)(v + 4) = *(const f32x4*)(yp + 8 * q + 4);
    *(f32x4*)(v + 8) = *(const f32x4*)(yp + 32 + 8 * q);
    *(f32x4*)(v + 12) = *(const f32x4*)(yp + 32 + 8 * q + 4);
    half8 xh[2], xl[2];
    split8(v, xh[0], xl[0]);
    split8(v + 8, xh[1], xl[1]);
#pragma unroll
    for (int mt = 0; mt < 4; ++mt) {
      const float* p0 = encW + (16 * mt + lm) * 64 + 8 * q;
      float w[8] __attribute__((aligned(16)));
      half8 eh, el;
      f32x4 a = *(const f32x4*)(encb + 16 * mt + 4 * q);
      *(f32x4*)(w) = *(const f32x4*)(p0);
      *(f32x4*)(w + 4) = *(const f32x4*)(p0 + 4);
      split8(w, eh, el);
      a = MFMA(eh, xh[0], a);
      a = MFMA(el, xh[0], a);
      a = MFMA(eh, xl[0], a);
      *(f32x4*)(w) = *(const f32x4*)(p0 + 32);
      *(f32x4*)(w + 4) = *(const f32x4*)(p0 + 36);
      split8(w, eh, el);
      a = MFMA(eh, xh[1], a);
      a = MFMA(el, xh[1], a);
      a = MFMA(eh, xl[1], a);
      zf[mt] = a;
    }
  }

  // ---- u0 = TS*(W1 z0 + b1) via transient L1 pass ----
  float u[8];
  {
    half8 t1h[2][2], t1l[2][2];
    f32x4 tb1[2];
#pragma unroll
    for (int mt = 0; mt < 2; ++mt) {
#pragma unroll
      for (int kt = 0; kt < 2; ++kt)
        load_wfrag(W1, 64, 16 * mt + lm, q, kt, TS, t1h[mt][kt], t1l[mt][kt]);
      f32x4 t1 = *(const f32x4*)(b1 + 16 * mt + 4 * q);
#pragma unroll
      for (int r = 0; r < 4; ++r) t1[r] *= TS;
      tb1[mt] = t1;
    }
    float zv[16];
#pragma unroll
    for (int mt = 0; mt < 4; ++mt)
#pragma unroll
      for (int r = 0; r < 4; ++r) zv[4 * mt + r] = zf[mt][r];
    half8 yh[2], yl[2];
    split8(zv, yh[0], yl[0]);
    split8(zv + 8, yh[1], yl[1]);
#pragma unroll
    for (int mt = 0; mt < 2; ++mt) {
      f32x4 a = tb1[mt];
      a = MFMA(t1h[mt][0], yh[0], a);
      a = MFMA(t1l[mt][0], yh[0], a);
      a = MFMA(t1h[mt][0], yl[0], a);
      a = MFMA(t1h[mt][1], yh[1], a);
      a = MFMA(t1l[mt][1], yh[1], a);
      a = MFMA(t1h[mt][1], yl[1], a);
#pragma unroll
      for (int r = 0; r < 4; ++r) u[4 * mt + r] = a[r];
    }
  }

  // ---- output helpers (read zf) ----
  auto store_z = [&](int s) {
    float* zb = out + (size_t)BN * TN * 64 + ((size_t)eg * TN + s) * 64;
#pragma unroll
    for (int mt = 0; mt < 4; ++mt) *(f32x4*)(zb + 16 * mt + 4 * q) = zf[mt];
  };
  auto dec_store = [&](int s) {
    half8 xh[2];
#pragma unroll
    for (int j = 0; j < 4; ++j) {
      xh[0][j] = (_Float16)zf[0][j];
      xh[0][4 + j] = (_Float16)zf[1][j];
      xh[1][j] = (_Float16)zf[2][j];
      xh[1][4 + j] = (_Float16)zf[3][j];
    }
    float* yb = out + ((size_t)eg * TN + s) * 64;
#pragma unroll
    for (int mt = 0; mt < 4; ++mt) {
      f32x4 a = decbf[mt];
      a = MFMA(dech[mt][0], xh[0], a);
      a = MFMA(dech[mt][1], xh[1], a);
      *(f32x4*)(yb + 16 * mt + 4 * q) = a;
    }
  };

  // ---- per-stage core: h1=tanh(p); q=W2h1+b2; h2=tanh(q); m=M*h2 ----
  auto layerchain = [&](const float (&pin)[8], float (&h2o)[8], float (&mo)[8]) {
    float h1[8];
#pragma unroll
    for (int j = 0; j < 8; ++j) h1[j] = tanh_pre(pin[j]);
    half8 hh, hl;
    split8(h1, hh, hl);
    float qv[8];
#pragma unroll
    for (int mt = 0; mt < 2; ++mt) {
      f32x4 a = b2f[mt];
      a = MFMA(w2h[mt], hh, a);
      a = MFMA(w2l[mt], hh, a);
      a = MFMA(w2h[mt], hl, a);
#pragma unroll
      for (int r = 0; r < 4; ++r) qv[4 * mt + r] = a[r];
    }
#pragma unroll
    for (int j = 0; j < 8; ++j) h2o[j] = tanh_pre(qv[j]);
    half8 th, tl;
    split8(h2o, th, tl);
#pragma unroll
    for (int mt = 0; mt < 2; ++mt) {
      f32x4 a = {0.0f, 0.0f, 0.0f, 0.0f};
      a = MFMA(Mh[mt], th, a);
      a = MFMA(Ml[mt], th, a);
      a = MFMA(Mh[mt], tl, a);
#pragma unroll
      for (int r = 0; r < 4; ++r) mo[4 * mt + r] = a[r];
    }
  };

  float H[8];  // sum_i dtB_i * h2_i  (drives z materialization)

  // ---- one full Tsit5 step in u-space ----
  auto stages = [&]() {
    float U[8], P3[8], P4[8], P5[8], P6[8], p[8], h2[8], m[8];
#pragma unroll
    for (int j = 0; j < 8; ++j) {
      U[j] = __builtin_fmaf(dt, c0[j], u[j]);
      P3[j] = __builtin_fmaf(sg3, c0[j], u[j]);
      P4[j] = __builtin_fmaf(sg4, c0[j], u[j]);
      P5[j] = __builtin_fmaf(sg5, c0[j], u[j]);
      P6[j] = __builtin_fmaf(sg6, c0[j], u[j]);
    }
    layerchain(u, h2, m);  // stage 1
#pragma unroll
    for (int j = 0; j < 8; ++j) {
      H[j] = d1 * h2[j];
      U[j] = __builtin_fmaf(d1, m[j], U[j]);
      P3[j] = __builtin_fmaf(c31, m[j], P3[j]);
      P4[j] = __builtin_fmaf(c41, m[j], P4[j]);
      P5[j] = __builtin_fmaf(c51, m[j], P5[j]);
      P6[j] = __builtin_fmaf(c61, m[j], P6[j]);
      p[j] = __builtin_fmaf(c21, c0[j] + m[j], u[j]);  // sig2 == c21
    }
    layerchain(p, h2, m);  // stage 2
#pragma unroll
    for (int j = 0; j < 8; ++j) {
      H[j] = __builtin_fmaf(d2, h2[j], H[j]);
      U[j] = __builtin_fmaf(d2, m[j], U[j]);
      P4[j] = __builtin_fmaf(c42, m[j], P4[j]);
      P5[j] = __builtin_fmaf(c52, m[j], P5[j]);
      P6[j] = __builtin_fmaf(c62, m[j], P6[j]);
      p[j] = __builtin_fmaf(c32, m[j], P3[j]);
    }
    layerchain(p, h2, m);  // stage 3
#pragma unroll
    for (int j = 0; j < 8; ++j) {
      H[j] = __builtin_fmaf(d3, h2[j], H[j]);
      U[j] = __builtin_fmaf(d3, m[j], U[j]);
      P5[j] = __builtin_fmaf(c53, m[j], P5[j]);
      P6[j] = __builtin_fmaf(c63, m[j], P6[j]);
      p[j] = __builtin_fmaf(c43, m[j], P4[j]);
    }
    layerchain(p, h2, m);  // stage 4
#pragma unroll
    for (int j = 0; j < 8; ++j) {
      H[j] = __builtin_fmaf(d4, h2[j], H[j]);
      U[j] = __builtin_fmaf(d4, m[j], U[j]);
      P6[j] = __builtin_fmaf(c64, m[j], P6[j]);
      p[j] = __builtin_fmaf(c54, m[j], P5[j]);
    }
    layerchain(p, h2, m);  // stage 5
#pragma unroll
    for (int j = 0; j < 8; ++j) {
      H[j] = __builtin_fmaf(d5, h2[j], H[j]);
      U[j] = __builtin_fmaf(d5, m[j], U[j]);
      p[j] = __builtin_fmaf(c65, m[j], P6[j]);
    }
    layerchain(p, h2, m);  // stage 6
#pragma unroll
    for (int j = 0; j < 8; ++j) {
      H[j] = __builtin_fmaf(d6, h2[j], H[j]);
      u[j] = __builtin_fmaf(d6, m[j], U[j]);  // u <- u_next
    }
  };

  // ---- z materialization for one step (off the u-chain): z += W3*H + dt*b3 ----
  auto zblock = [&](int s) {
    half8 Hh, Hl;
    split8(H, Hh, Hl);
#pragma unroll
    for (int mt = 0; mt < 4; ++mt) {
      f32x4 a = zf[mt];
      a = MFMA(w3h[mt], Hh, a);
      a = MFMA(w3l[mt], Hh, a);
      a = MFMA(w3h[mt], Hl, a);
      zf[mt] = a + db3f[mt];
    }
    store_z(s);
    dec_store(s);
  };

  store_z(0);
  dec_store(0);

  stages();  // step 1
#pragma nounroll
  for (int s = 2; s < TN; ++s) {
    zblock(s - 1);  // materialize + store step s-1 (independent of the u-chain below;
    stages();       //  compiler interleaves its MFMAs/stores into stage-1/2 stalls)
  }
  zblock(TN - 1);
}

extern "C" void kernel_launch(void* const* d_in, const int* in_sizes, int n_in,
                              void* d_out, int out_size, void* d_ws, size_t ws_size,
                              hipStream_t stream) {
  const float* ts = (const float*)d_in[0];
  const float* y0 = (const float*)d_in[1];
  const float* encW = (const float*)d_in[2];
  const float* encb = (const float*)d_in[3];
  const float* W1 = (const float*)d_in[4];
  const float* b1 = (const float*)d_in[5];
  const float* W2 = (const float*)d_in[6];
  const float* b2 = (const float*)d_in[7];
  const float* W3 = (const float*)d_in[8];
  const float* b3 = (const float*)d_in[9];
  const float* decW = (const float*)d_in[10];
  const float* decb = (const float*)d_in[11];
  node_kernel<<<BN / 16, 64, 0, stream>>>(ts, y0, encW, encb, W1, b1, W2, b2, W3, b3, decW,
                                          decb, (float*)d_out);
}